// Round 1
// baseline (1419.780 us; speedup 1.0000x reference)
//
#include <hip/hip_runtime.h>
#include <math.h>

// Problem constants (match reference)
#define BB 32
#define SS 128
#define II 64
#define HH 1024
#define TT 4
constexpr float DECAY   = 0.9f;
constexpr float THRESH  = 1.0f;
constexpr float BETA    = 5.0f;

// -----------------------------------------------------------------------------
// Kernel 1: drive[b,s,h] = sum_i x[b,s,i,h] * enc[i,h]
// One thread per float4 of h. Fully coalesced 16B/lane loads of x (the 1 GiB
// stream). enc (256 KB) stays L2-resident.
// -----------------------------------------------------------------------------
__global__ __launch_bounds__(256) void drive_kernel(
    const float4* __restrict__ x,      // [B*S, I, H/4]
    const float4* __restrict__ enc,    // [I, H/4]
    float4* __restrict__ drive)        // [B*S, H/4]
{
    const int tid = blockIdx.x * blockDim.x + threadIdx.x;   // [0, B*S*H/4)
    const int hq  = tid & (HH / 4 - 1);                       // h/4
    const int bs  = tid >> 8;                                 // H/4 == 256
    const float4* xp = x   + (size_t)bs * II * (HH / 4) + hq;
    const float4* ep = enc + hq;
    float4 acc = make_float4(0.f, 0.f, 0.f, 0.f);
#pragma unroll 8
    for (int i = 0; i < II; ++i) {
        float4 xv = xp[i * (HH / 4)];
        float4 ev = ep[i * (HH / 4)];
        acc.x = fmaf(xv.x, ev.x, acc.x);
        acc.y = fmaf(xv.y, ev.y, acc.y);
        acc.z = fmaf(xv.z, ev.z, acc.z);
        acc.w = fmaf(xv.w, ev.w, acc.w);
    }
    drive[tid] = acc;
}

// -----------------------------------------------------------------------------
// Kernel 2: sequential LIF scan. One thread per (b,h) chain; 512 blocks of 64
// so all 256 CUs get work. drive[s+1] prefetched while the 4 sub-steps of s
// compute, hiding L2 latency at 2-waves/CU occupancy.
// -----------------------------------------------------------------------------
__global__ __launch_bounds__(64) void lif_kernel(
    const float* __restrict__ drive,   // [B, S, H]
    float* __restrict__ out,           // [B, S*T, H]
    float* __restrict__ vfinal)        // [B, H]
{
    const int tid = blockIdx.x * blockDim.x + threadIdx.x;   // [0, B*H)
    const int h   = tid & (HH - 1);
    const int b   = tid >> 10;                                // H == 1024
    const float* dp = drive + (size_t)b * SS * HH + h;
    float*       op = out   + (size_t)b * SS * TT * HH + h;

    float v = 0.f;
    float d = dp[0];
    for (int s = 0; s < SS; ++s) {
        float dn = (s + 1 < SS) ? dp[(size_t)(s + 1) * HH] : 0.f;  // prefetch
#pragma unroll
        for (int t = 0; t < TT; ++t) {
            v = fmaf(DECAY, v, d);
            float z  = BETA * (v - THRESH);
            float sp = 1.f / (1.f + expf(-z));
            v -= sp * THRESH;
            op[(size_t)(s * TT + t) * HH] = sp;
        }
        d = dn;
    }
    vfinal[tid] = v;
}

// -----------------------------------------------------------------------------
// Fallback: fully fused (used only if ws_size can't hold drive). One thread per
// (b,h); encoding column held in registers.
// -----------------------------------------------------------------------------
__global__ __launch_bounds__(64) void fused_kernel(
    const float* __restrict__ x,
    const float* __restrict__ enc,
    float* __restrict__ out,
    float* __restrict__ vfinal)
{
    const int tid = blockIdx.x * blockDim.x + threadIdx.x;
    const int h   = tid & (HH - 1);
    const int b   = tid >> 10;
    float e[II];
#pragma unroll
    for (int i = 0; i < II; ++i) e[i] = enc[i * HH + h];

    float* op = out + (size_t)b * SS * TT * HH + h;
    float v = 0.f;
    for (int s = 0; s < SS; ++s) {
        const float* xp = x + ((size_t)(b * SS + s) * II) * HH + h;
        float acc = 0.f;
#pragma unroll
        for (int i = 0; i < II; ++i) acc = fmaf(xp[(size_t)i * HH], e[i], acc);
#pragma unroll
        for (int t = 0; t < TT; ++t) {
            v = fmaf(DECAY, v, acc);
            float z  = BETA * (v - THRESH);
            float sp = 1.f / (1.f + expf(-z));
            v -= sp * THRESH;
            op[(size_t)(s * TT + t) * HH] = sp;
        }
    }
    vfinal[tid] = v;
}

extern "C" void kernel_launch(void* const* d_in, const int* in_sizes, int n_in,
                              void* d_out, int out_size, void* d_ws, size_t ws_size,
                              hipStream_t stream) {
    const float* x   = (const float*)d_in[0];   // [B,S,I,H]
    const float* enc = (const float*)d_in[1];   // [I,H]
    float* out    = (float*)d_out;                        // [B,S*T,H] then [B,H]
    float* vfinal = out + (size_t)BB * SS * TT * HH;      // concatenated flat

    const size_t drive_bytes = (size_t)BB * SS * HH * sizeof(float);  // 16.8 MB

    if (ws_size >= drive_bytes) {
        float* drive = (float*)d_ws;
        {
            const int n4 = BB * SS * (HH / 4);   // 1,048,576 threads
            drive_kernel<<<n4 / 256, 256, 0, stream>>>(
                (const float4*)x, (const float4*)enc, (float4*)drive);
        }
        {
            const int n = BB * HH;               // 32,768 threads
            lif_kernel<<<n / 64, 64, 0, stream>>>(drive, out, vfinal);
        }
    } else {
        const int n = BB * HH;
        fused_kernel<<<n / 64, 64, 0, stream>>>(x, enc, out, vfinal);
    }
}